// Round 13
// baseline (78.638 us; speedup 1.0000x reference)
//
#include <hip/hip_runtime.h>
#include <stdint.h>

#define IN_F   4096
#define OUT_F  11008
#define BATCH  8
#define WAVES  4
#define RPW    2                  // rows per wave
#define RPB    (WAVES*RPW)        // 8 rows per block
#define CHUNK  128                // i-values per chunk
#define NCHUNK (IN_F/CHUNK)       // 32
#define NSLOT  4                  // LDS ring slots (prefetch depth 3)
#define SLOTI  (3*RPB*CHUNK)      // ints per slot: 3072 (stored | sign | x)

typedef __attribute__((address_space(1))) const uint32_t* gas_t;
typedef __attribute__((address_space(3))) uint32_t* las_t;

// async global->LDS DMA, 16 B/lane: per-lane global address, wave-uniform
// LDS base (+lane*16 implicit). No VGPR destination -> regalloc-proof.
#define DMA16(gsrc, ldst) \
    __builtin_amdgcn_global_load_lds((gas_t)(gsrc), (las_t)(ldst), 16, 0, 0)

#define SBAR() __builtin_amdgcn_sched_barrier(0)
// counted wait: chunk k's 3 DMAs retired, later chunks' stay IN FLIGHT
#define VWAIT(N)                                                             \
    do {                                                                     \
        asm volatile("s_waitcnt vmcnt(" #N ")" ::: "memory");                \
        SBAR();                                                              \
    } while (0)

__device__ __forceinline__ float qins_decode(int code, int sgn, float d0, float d1) {
    // |w| = exp2(d0 + code*d1); sign bit straight from the int32 sign (+1 / -1)
    const float e = __builtin_amdgcn_exp2f(fmaf((float)code, d1, d0));
    const uint32_t m = ((uint32_t)sgn) & 0x80000000u;
    return __uint_as_float(__float_as_uint(e) ^ m);
}

__global__ __launch_bounds__(256, 3)
void qins_linear_kernel(const float* __restrict__ x,
                        const uint32_t* __restrict__ stored,
                        const uint32_t* __restrict__ sign,
                        const float* __restrict__ log_min,
                        const float* __restrict__ log_max,
                        const float* __restrict__ bias,
                        float* __restrict__ out)
{
    // slot (ints): [0,1024) stored 8x128 | [1024,2048) sign | [2048,3072) x 8x128
    // wave w stages rows/batches {2w,2w+1}: lanes 0-31 -> first, 32-63 -> second
    __shared__ int lds[NSLOT][SLOTI];

    const int tid  = threadIdx.x;
    const int lane = tid & 63;
    const int wave = tid >> 6;
    const int o0   = blockIdx.x * RPB;

    const float lmin = log_min[0];
    const float lmax = log_max[0];
    const float L2E  = 1.44269504088896340736f;
    // log2(|w|) = d0 + code*d1
    const float d1 = -(lmax - lmin) * (L2E / 254.0f);
    const float d0 = (lmin + (lmax - lmin) * (255.0f / 254.0f)) * L2E;

    const int sub = lane >> 5;
    const int i32 = (lane & 31) * 4;
    const uint32_t* gs = stored + (size_t)(o0 + 2 * wave + sub) * IN_F + i32;
    const uint32_t* gg = sign   + (size_t)(o0 + 2 * wave + sub) * IN_F + i32;
    const uint32_t* gx = (const uint32_t*)x + (size_t)(2 * wave + sub) * IN_F + i32;

#define ISSUE(T, K)                                                          \
    do {                                                                     \
        const int _ip = (K) * CHUNK;                                         \
        DMA16(gs + _ip, &lds[T][wave * 256]);                                \
        DMA16(gg + _ip, &lds[T][1024 + wave * 256]);                         \
        DMA16(gx + _ip, &lds[T][2048 + wave * 256]);                         \
    } while (0)

    float acc[RPW][BATCH];
#pragma unroll
    for (int r = 0; r < RPW; ++r)
#pragma unroll
        for (int b = 0; b < BATCH; ++b) acc[r][b] = 0.0f;

    // prologue: chunks 0,1,2 in flight (9 outstanding DMAs per wave)
    ISSUE(0, 0);
    ISSUE(1, 1);
    ISSUE(2, 2);
    SBAR();

#pragma unroll 1
    for (int k = 0; k < NCHUNK; ++k) {
        // retire exactly chunk k's DMAs; keep later chunks in flight
        if (k < NCHUNK - 2)       VWAIT(6);
        else if (k == NCHUNK - 2) VWAIT(3);
        else                      VWAIT(0);
        __builtin_amdgcn_s_barrier();   // raw barrier: NO vmcnt(0) drain
        SBAR();

        if (k + 3 < NCHUNK)
            ISSUE((k + 3) & (NSLOT - 1), k + 3);   // refill reclaimed slot
        SBAR();

        // compute chunk k: rows 2w,2w+1; lane covers i = 2*lane, 2*lane+1
        {
            const int cur = k & (NSLOT - 1);
            const int li  = lane * 2;
            const int2 c0 = *reinterpret_cast<const int2*>(&lds[cur][wave * 256 + li]);
            const int2 c1 = *reinterpret_cast<const int2*>(&lds[cur][wave * 256 + 128 + li]);
            const int2 g0 = *reinterpret_cast<const int2*>(&lds[cur][1024 + wave * 256 + li]);
            const int2 g1 = *reinterpret_cast<const int2*>(&lds[cur][1024 + wave * 256 + 128 + li]);
            const float w00 = qins_decode(c0.x, g0.x, d0, d1);
            const float w01 = qins_decode(c0.y, g0.y, d0, d1);
            const float w10 = qins_decode(c1.x, g1.x, d0, d1);
            const float w11 = qins_decode(c1.y, g1.y, d0, d1);
#pragma unroll
            for (int b = 0; b < BATCH; ++b) {
                const float2 xv = *reinterpret_cast<const float2*>(
                    &lds[cur][2048 + (b >> 1) * 256 + (b & 1) * 128 + li]);
                acc[0][b] = fmaf(w01, xv.y, fmaf(w00, xv.x, acc[0][b]));
                acc[1][b] = fmaf(w11, xv.y, fmaf(w10, xv.x, acc[1][b]));
            }
        }
    }

    // butterfly reduction of the 16 (row,batch) partials across the wave
#pragma unroll
    for (int r = 0; r < RPW; ++r)
#pragma unroll
        for (int b = 0; b < BATCH; ++b) {
            float v = acc[r][b];
#pragma unroll
            for (int s = 32; s >= 1; s >>= 1)
                v += __shfl_xor(v, s, 64);
            acc[r][b] = v;
        }

    if (lane == 0) {
#pragma unroll
        for (int r = 0; r < RPW; ++r) {
            const int row = o0 + 2 * wave + r;
            const float bv = bias[row];
#pragma unroll
            for (int b = 0; b < BATCH; ++b)
                out[(size_t)b * OUT_F + row] = acc[r][b] + bv;
        }
    }
#undef ISSUE
}

extern "C" void kernel_launch(void* const* d_in, const int* in_sizes, int n_in,
                              void* d_out, int out_size, void* d_ws, size_t ws_size,
                              hipStream_t stream)
{
    const float*    x      = (const float*)d_in[0];
    const uint32_t* stored = (const uint32_t*)d_in[1];
    const uint32_t* sign   = (const uint32_t*)d_in[2];
    const float*    lmin   = (const float*)d_in[3];
    const float*    lmax   = (const float*)d_in[4];
    const float*    bias   = (const float*)d_in[5];
    float* out = (float*)d_out;

    dim3 grid(OUT_F / RPB), block(WAVES * 64);
    qins_linear_kernel<<<grid, block, 0, stream>>>(x, stored, sign, lmin, lmax, bias, out);
}